// Round 2
// baseline (760.714 us; speedup 1.0000x reference)
//
#include <hip/hip_runtime.h>

#define NS 128
#define NP 32
#define HD 32
#define ED 16
#define GH 72
#define GO 8
#define MD 64
#define TT 8
#define NB (NS*NP)

__device__ __forceinline__ float sigm(float x){ return 1.0f/(1.0f+__expf(-x)); }
__device__ __forceinline__ float tanhfast(float x){ return 1.0f - 2.0f/(__expf(2.0f*x)+1.0f); }

__global__ __launch_bounds__(512, 1) void decoder_kernel(
    const float* __restrict__ last_pos, const float* __restrict__ last_pos_rel,
    const float* __restrict__ hh, const float* __restrict__ ch,
    const int*  __restrict__ eg,
    const float* __restrict__ W_se, const float* __restrict__ b_se,
    const float* __restrict__ Wih, const float* __restrict__ Whh,
    const float* __restrict__ bih, const float* __restrict__ bhh,
    const float* __restrict__ W_hp, const float* __restrict__ b_hp,
    const float* __restrict__ W_pse, const float* __restrict__ b_pse,
    const float* __restrict__ W1a, const float* __restrict__ W2a,
    const float* __restrict__ W1b, const float* __restrict__ W2b,
    const float* __restrict__ W_m1, const float* __restrict__ b_m1,
    const float* __restrict__ W_m2, const float* __restrict__ b_m2,
    float* __restrict__ out)
{
  const int tid = threadIdx.x;
  const int scn = blockIdx.x;

  // a_ rows padded to 76 floats: 76/4=19 (odd) -> conflict-minimal b128, rows 16B aligned
  __shared__ __align__(16) float a_[2][NP][76];
  __shared__ __align__(16) float e_[2][NP][GH];
  __shared__ __align__(16) float GS[2][5][GH];
  __shared__ __align__(16) float W2l[2][GH][GO];
  __shared__ float Wp1[2][2][GH];
  __shared__ float c1l[2][GH];
  __shared__ float hbuf[NP][HD];
  __shared__ float h2buf[NP][HD];
  __shared__ float cbuf[NP][HD];
  __shared__ float xbuf[NP][ED];
  __shared__ float lpbuf[NP][2];
  __shared__ float rpbuf[NP][2];
  __shared__ float phbuf[NP][2*GO];
  __shared__ unsigned bm[2][NP];
  __shared__ float invn[2][NP];
  __shared__ int gl[NP];

  // ---------------- setup ----------------
  if (tid < NP) {
    int gi = eg[scn*NP + tid];
    gl[tid] = gi;
    unsigned sm = 0;
    for (int j = 0; j < NP; j++) {
      int gj = eg[scn*NP + j];
      bool sj = (j == tid) || (gi == gj && gi != 0);
      sm |= ((unsigned)sj) << j;
    }
    unsigned dm = (~sm) | (1u << tid);
    bm[0][tid] = sm; bm[1][tid] = dm;
    invn[0][tid] = 1.0f/(float)__popc(sm);
    invn[1][tid] = 1.0f/(float)__popc(dm);
  }
  // h, c init (1024 units)
  for (int r = 0; r < 2; r++) {
    int u = tid + 512*r;
    int p = u >> 5, n = u & 31;
    hbuf[p][n] = hh[(scn*NP+p)*HD + n];
    cbuf[p][n] = ch[(scn*NP+p)*HD + n];
  }
  // x init = last_pos_rel @ W_se + b_se  (512 units)
  {
    int p = tid >> 4, e2 = tid & 15;
    float r0 = last_pos_rel[(scn*NP+p)*2+0];
    float r1 = last_pos_rel[(scn*NP+p)*2+1];
    xbuf[p][e2] = b_se[e2] + r0*W_se[e2] + r1*W_se[ED+e2];
  }
  if (tid < 64) {
    int p = tid >> 1, k = tid & 1;
    lpbuf[p][k] = last_pos[(scn*NP+p)*2+k];
  }
  // folded Wp1 = W_pse @ W1[:16], c1 = b_pse @ W1[:16]
  if (tid < 2*GH) {
    int m = tid / GH, d = tid % GH;
    const float* W1 = m ? W1b : W1a;
    float s0 = 0.f, s1 = 0.f, sc1 = 0.f;
    for (int e2 = 0; e2 < ED; e2++) {
      float w = W1[e2*GH + d];
      s0  += W_pse[e2]    * w;
      s1  += W_pse[ED+e2] * w;
      sc1 += b_pse[e2]    * w;
    }
    Wp1[m][0][d] = s0; Wp1[m][1][d] = s1; c1l[m][d] = sc1;
  }
  // W2 staging (1152 units)
  for (int r = 0; r < 3; r++) {
    int u = tid + 512*r;
    if (u < 2*GH*GO) {
      int m = u/(GH*GO), rest = u%(GH*GO), d = rest/GO, o = rest%GO;
      const float* W2 = m ? W2b : W2a;
      W2l[m][d][o] = W2[d*GO + o];
    }
  }
  __syncthreads();

  // ---------------- time steps ----------------
  for (int t = 0; t < TT; t++) {
    // phase 1a: LSTM cell. unit = (ped, hidden n); gates i,f,g,o
    for (int r = 0; r < 2; r++) {
      int u = tid + 512*r;
      int p = u >> 5, n = u & 31;
      float acc[4];
      #pragma unroll
      for (int g = 0; g < 4; g++) acc[g] = bih[g*HD+n] + bhh[g*HD+n];
      float xv[ED];
      #pragma unroll
      for (int e2 = 0; e2 < ED; e2++) xv[e2] = xbuf[p][e2];
      float hv[HD];
      #pragma unroll
      for (int k = 0; k < HD; k++) hv[k] = hbuf[p][k];
      #pragma unroll
      for (int g = 0; g < 4; g++) {
        int row = g*HD + n;
        const float4* wx = (const float4*)(Wih + row*ED);
        #pragma unroll
        for (int c4 = 0; c4 < 4; c4++) {
          float4 w = wx[c4];
          acc[g] = fmaf(xv[c4*4+0], w.x, acc[g]);
          acc[g] = fmaf(xv[c4*4+1], w.y, acc[g]);
          acc[g] = fmaf(xv[c4*4+2], w.z, acc[g]);
          acc[g] = fmaf(xv[c4*4+3], w.w, acc[g]);
        }
        const float4* wh = (const float4*)(Whh + row*HD);
        #pragma unroll
        for (int c4 = 0; c4 < 8; c4++) {
          float4 w = wh[c4];
          acc[g] = fmaf(hv[c4*4+0], w.x, acc[g]);
          acc[g] = fmaf(hv[c4*4+1], w.y, acc[g]);
          acc[g] = fmaf(hv[c4*4+2], w.z, acc[g]);
          acc[g] = fmaf(hv[c4*4+3], w.w, acc[g]);
        }
      }
      float ig = sigm(acc[0]), fg = sigm(acc[1]);
      float gg = tanhfast(acc[2]), og = sigm(acc[3]);
      float c2 = fg*cbuf[p][n] + ig*gg;
      cbuf[p][n] = c2;
      h2buf[p][n] = og * tanhfast(c2);
    }
    __syncthreads();

    // phase 1b: rel_pos = h2 @ W_hp + b_hp; cur = rel+lp; emit output
    if (tid < 64) {
      int p = tid >> 1, k = tid & 1;
      float rp = b_hp[k];
      for (int hk = 0; hk < HD; hk++) rp = fmaf(h2buf[p][hk], W_hp[hk*2+k], rp);
      rpbuf[p][k] = rp;
      out[t*NB*2 + (scn*NP+p)*2 + k] = rp;
      lpbuf[p][k] += rp;
    }
    __syncthreads();

    // phase 2: a_[m][j][d] = pos_j@Wp1 + h2_j@W1[16:]; e_[m][i][d] = c1 - pos_i@Wp1; x-next
    for (int r = 0; r < 10; r++) {
      int u = tid + 512*r;
      if (u < 2*NP*GH) {
        int m = u/(NP*GH), rest = u%(NP*GH), j = rest/GH, d = rest%GH;
        float pp = lpbuf[j][0]*Wp1[m][0][d] + lpbuf[j][1]*Wp1[m][1][d];
        const float* W1 = m ? W1b : W1a;
        float av = pp;
        for (int hk = 0; hk < HD; hk++)
          av = fmaf(h2buf[j][hk], W1[(ED+hk)*GH + d], av);
        a_[m][j][d] = av;
        e_[m][j][d] = c1l[m][d] - pp;
      } else {
        int u2 = u - 2*NP*GH;   // [0,512): next x = rel_pos @ W_se + b_se
        int p = u2 >> 4, e2 = u2 & 15;
        xbuf[p][e2] = b_se[e2] + rpbuf[p][0]*W_se[e2] + rpbuf[p][1]*W_se[ED+e2];
      }
    }
    __syncthreads();

    // phase 2b: group sums over a_: GS[0][G]=A_G (same); GS[1][0]=tot, GS[1][G]=tot-A_G (diff)
    if (tid < 2*GH) {
      int m = tid / GH, d = tid % GH;
      float tot = 0.f, g1 = 0.f, g2 = 0.f, g3 = 0.f, g4 = 0.f;
      for (int j = 0; j < NP; j++) {
        float v = a_[m][j][d];
        int gj = gl[j];
        tot += v;
        g1 += (gj==1) ? v : 0.0f;
        g2 += (gj==2) ? v : 0.0f;
        g3 += (gj==3) ? v : 0.0f;
        g4 += (gj==4) ? v : 0.0f;
      }
      if (m == 0) {
        GS[0][0][d]=tot;
        GS[0][1][d]=g1; GS[0][2][d]=g2; GS[0][3][d]=g3; GS[0][4][d]=g4;
      } else {
        GS[1][0][d]=tot;
        GS[1][1][d]=tot-g1; GS[1][2][d]=tot-g2; GS[1][3][d]=tot-g3; GS[1][4][d]=tot-g4;
      }
    }
    __syncthreads();

    // phase 3: pool. task=(m,i,j); j = lane & 31 within 32-lane group
    for (int r = 0; r < 4; r++) {
      int task = tid + 512*r;
      int j = task & 31, i = (task >> 5) & 31, m = task >> 10;
      unsigned bmv = bm[m][i];
      bool mij = (bmv >> j) & 1u;
      bool diag = (i == j);
      int gi = gl[i];
      float in_ = invn[m][i];
      const float *p0, *p1;
      float c0, c1c;
      if (diag) {
        if (m == 0) {
          p0 = gi ? &GS[0][gi][0] : &a_[0][i][0];
          c0 = in_; p1 = &a_[0][i][0]; c1c = 0.0f;
        } else {
          p0 = &GS[1][gi][0];            // gi==0 -> tot row
          c0 = in_; p1 = &a_[1][i][0]; c1c = gi ? in_ : 0.0f;
        }
      } else if (mij) {
        p0 = &a_[m][j][0]; c0 = 0.5f; p1 = &a_[m][i][0]; c1c = 0.5f;
      } else {
        p0 = &a_[m][j][0]; c0 = 1.0f; p1 = &a_[m][j][0]; c1c = 0.0f;
      }
      const float* ep = &e_[m][i][0];

      float q[8] = {0,0,0,0,0,0,0,0};
      for (int d4 = 0; d4 < GH/4; d4++) {
        float4 va = *(const float4*)(p0 + d4*4);
        float4 vb = *(const float4*)(p1 + d4*4);
        float4 ve = *(const float4*)(ep + d4*4);
        float tv[4];
        tv[0] = fmaxf(fmaf(c0, va.x, fmaf(c1c, vb.x, ve.x)), 0.f);
        tv[1] = fmaxf(fmaf(c0, va.y, fmaf(c1c, vb.y, ve.y)), 0.f);
        tv[2] = fmaxf(fmaf(c0, va.z, fmaf(c1c, vb.z, ve.z)), 0.f);
        tv[3] = fmaxf(fmaf(c0, va.w, fmaf(c1c, vb.w, ve.w)), 0.f);
        #pragma unroll
        for (int k = 0; k < 4; k++) {
          const float4* w2 = (const float4*)&W2l[m][d4*4+k][0];
          float4 wa = w2[0], wb = w2[1];
          q[0]=fmaf(tv[k],wa.x,q[0]); q[1]=fmaf(tv[k],wa.y,q[1]);
          q[2]=fmaf(tv[k],wa.z,q[2]); q[3]=fmaf(tv[k],wa.w,q[3]);
          q[4]=fmaf(tv[k],wb.x,q[4]); q[5]=fmaf(tv[k],wb.y,q[5]);
          q[6]=fmaf(tv[k],wb.z,q[6]); q[7]=fmaf(tv[k],wb.w,q[7]);
        }
      }
      // masked sum over j (layer-2 diag, post-W2); xor masks <32 stay in 32-lane half
      float sq[8];
      #pragma unroll
      for (int o = 0; o < 8; o++) sq[o] = mij ? q[o] : 0.0f;
      #pragma unroll
      for (int off = 1; off < 32; off <<= 1) {
        #pragma unroll
        for (int o = 0; o < 8; o++) sq[o] += __shfl_xor(sq[o], off);
      }
      // broadcast q_ii from the diag lane
      float qd[8];
      #pragma unroll
      for (int o = 0; o < 8; o++) qd[o] = __shfl(q[o], i, 32);
      float F[8];
      if (diag) {
        #pragma unroll
        for (int o = 0; o < 8; o++) F[o] = fmaxf(sq[o]*in_, 0.f);
      } else {
        float scl = mij ? 0.5f : 1.0f;
        #pragma unroll
        for (int o = 0; o < 8; o++)
          F[o] = fmaxf((q[o] + (mij ? qd[o] : 0.f))*scl, 0.f);
      }
      // max over j
      #pragma unroll
      for (int off = 1; off < 32; off <<= 1) {
        #pragma unroll
        for (int o = 0; o < 8; o++) F[o] = fmaxf(F[o], __shfl_xor(F[o], off));
      }
      if (j == 0) {
        #pragma unroll
        for (int o = 0; o < 8; o++) phbuf[i][m*GO + o] = F[o];
      }
    }
    __syncthreads();

    // phase 4: mlp (48 -> 64 -> 32, relu both). 32 lanes per ped.
    {
      int grp = tid >> 5;     // 16 groups of 32 lanes
      int u = tid & 31;
      for (int r = 0; r < 2; r++) {
        int p = grp + 16*r;
        float m1lo = b_m1[u];
        float m1hi = b_m1[32 + u];
        for (int k = 0; k < HD; k++) {
          float hv = h2buf[p][k];
          m1lo = fmaf(hv, W_m1[k*MD + u],      m1lo);
          m1hi = fmaf(hv, W_m1[k*MD + 32 + u], m1hi);
        }
        for (int k = 0; k < 2*GO; k++) {
          float pv = phbuf[p][k];
          m1lo = fmaf(pv, W_m1[(HD+k)*MD + u],      m1lo);
          m1hi = fmaf(pv, W_m1[(HD+k)*MD + 32 + u], m1hi);
        }
        m1lo = fmaxf(m1lo, 0.f); m1hi = fmaxf(m1hi, 0.f);
        float acc = b_m2[u];
        for (int k = 0; k < 32; k++) {
          float v = __shfl(m1lo, k, 32);
          acc = fmaf(v, W_m2[k*HD + u], acc);
        }
        for (int k = 0; k < 32; k++) {
          float v = __shfl(m1hi, k, 32);
          acc = fmaf(v, W_m2[(32+k)*HD + u], acc);
        }
        hbuf[p][u] = fmaxf(acc, 0.f);
      }
    }
    __syncthreads();
  }
}

extern "C" void kernel_launch(void* const* d_in, const int* in_sizes, int n_in,
                              void* d_out, int out_size, void* d_ws, size_t ws_size,
                              hipStream_t stream) {
  (void)in_sizes; (void)n_in; (void)out_size; (void)d_ws; (void)ws_size;
  const float* last_pos     = (const float*)d_in[0];
  const float* last_pos_rel = (const float*)d_in[1];
  const float* hh           = (const float*)d_in[2];
  const float* ch           = (const float*)d_in[3];
  // d_in[4] = seq_start_end (uniform scenes; unused)
  const int*  eg            = (const int*) d_in[5];
  const float* W_se  = (const float*)d_in[6];
  const float* b_se  = (const float*)d_in[7];
  const float* Wih   = (const float*)d_in[8];
  const float* Whh   = (const float*)d_in[9];
  const float* bih   = (const float*)d_in[10];
  const float* bhh   = (const float*)d_in[11];
  const float* W_hp  = (const float*)d_in[12];
  const float* b_hp  = (const float*)d_in[13];
  const float* W_pse = (const float*)d_in[14];
  const float* b_pse = (const float*)d_in[15];
  const float* W1a   = (const float*)d_in[16];
  const float* W2a   = (const float*)d_in[17];
  const float* W1b   = (const float*)d_in[18];
  const float* W2b   = (const float*)d_in[19];
  const float* W_m1  = (const float*)d_in[20];
  const float* b_m1  = (const float*)d_in[21];
  const float* W_m2  = (const float*)d_in[22];
  const float* b_m2  = (const float*)d_in[23];
  float* out = (float*)d_out;

  decoder_kernel<<<NS, 512, 0, stream>>>(
      last_pos, last_pos_rel, hh, ch, eg,
      W_se, b_se, Wih, Whh, bih, bhh, W_hp, b_hp, W_pse, b_pse,
      W1a, W2a, W1b, W2b, W_m1, b_m1, W_m2, b_m2, out);
}

// Round 3
// 724.719 us; speedup vs baseline: 1.0497x; 1.0497x over previous
//
#include <hip/hip_runtime.h>

#define NS 128
#define NP 32
#define HD 32
#define ED 16
#define GH 72
#define GO 8
#define MD 64
#define TT 8
#define NB (NS*NP)

typedef float v2f __attribute__((ext_vector_type(2)));

__device__ __forceinline__ float sigm(float x){ return 1.0f/(1.0f+__expf(-x)); }
__device__ __forceinline__ float tanhfast(float x){ return 1.0f - 2.0f/(__expf(2.0f*x)+1.0f); }

__global__ __launch_bounds__(512, 2) void decoder_kernel(
    const float* __restrict__ last_pos, const float* __restrict__ last_pos_rel,
    const float* __restrict__ hh, const float* __restrict__ ch,
    const int*  __restrict__ eg,
    const float* __restrict__ W_se, const float* __restrict__ b_se,
    const float* __restrict__ Wih, const float* __restrict__ Whh,
    const float* __restrict__ bih, const float* __restrict__ bhh,
    const float* __restrict__ W_hp, const float* __restrict__ b_hp,
    const float* __restrict__ W_pse, const float* __restrict__ b_pse,
    const float* __restrict__ W1a, const float* __restrict__ W2a,
    const float* __restrict__ W1b, const float* __restrict__ W2b,
    const float* __restrict__ W_m1, const float* __restrict__ b_m1,
    const float* __restrict__ W_m2, const float* __restrict__ b_m2,
    float* __restrict__ out)
{
  const int tid  = threadIdx.x;
  const int scn  = blockIdx.x;
  const int lane = tid & 31;   // j / n / u within 32-group
  const int grp  = tid >> 5;   // 0..15

  // uni overlays: G[32][128] (LSTM gate staging, 16 KB)  <->  a1[32][76] + e1[32][76] (19 KB)
  __shared__ __align__(16) float uni[4864];
  __shared__ __align__(16) float GS1[5][GH];
  __shared__ __align__(16) float W2l[2][GH][GO];
  __shared__ float Wp1[2][2][GH];
  __shared__ float c1l[2][GH];
  __shared__ __align__(16) float hbuf[NP][36];   // 36: rows 16B-aligned for b128
  __shared__ float h2buf[NP][33];                // 33: conflict-free column reads
  __shared__ float lpbuf[NP][2];
  __shared__ float rpbuf[NP][2];
  __shared__ float phbuf[NP][16];
  __shared__ float Whp[NP][2];
  __shared__ float bhp[2];
  __shared__ unsigned bm[2][NP];
  __shared__ float invn[2][NP];
  __shared__ int gl[NP];

  float* const a1 = uni;            // [32][76]
  float* const e1 = uni + NP*76;    // [32][76]

  // ---------- persistent per-thread LSTM row weights (read global ONCE) ----------
  const int myrow = tid & 127;      // gate row 0..127
  const int pq    = tid >> 7;       // 0..3 -> 8 peds each
  float wrow[HD];
  #pragma unroll
  for (int c = 0; c < HD/4; c++) {
    float4 w = *(const float4*)(Whh + myrow*HD + c*4);
    wrow[c*4+0]=w.x; wrow[c*4+1]=w.y; wrow[c*4+2]=w.z; wrow[c*4+3]=w.w;
  }
  float wf0 = 0.f, wf1 = 0.f, bfr = bih[myrow] + bhh[myrow];
  #pragma unroll
  for (int e = 0; e < ED; e++) {
    float wv = Wih[myrow*ED + e];
    wf0 = fmaf(W_se[e],    wv, wf0);
    wf1 = fmaf(W_se[ED+e], wv, wf1);
    bfr = fmaf(b_se[e],    wv, bfr);
  }

  // ---------- persistent cell state (thread owns cells (grp,lane),(grp+16,lane)) ----------
  float creg[2];
  {
    int n = lane;
    creg[0] = ch[(scn*NP + grp     )*HD + n];
    creg[1] = ch[(scn*NP + grp + 16)*HD + n];
    hbuf[grp     ][n] = hh[(scn*NP + grp     )*HD + n];
    hbuf[grp + 16][n] = hh[(scn*NP + grp + 16)*HD + n];
  }

  // ---------- setup ----------
  if (tid < NP) {
    int gi = eg[scn*NP + tid];
    gl[tid] = gi;
    unsigned sm = 0;
    for (int j = 0; j < NP; j++) {
      int gj = eg[scn*NP + j];
      bool sj = (j == tid) || (gi == gj && gi != 0);
      sm |= ((unsigned)sj) << j;
    }
    unsigned dm = (~sm) | (1u << tid);
    bm[0][tid] = sm; bm[1][tid] = dm;
    invn[0][tid] = 1.0f/(float)__popc(sm);
    invn[1][tid] = 1.0f/(float)__popc(dm);
  }
  if (tid < 64) {
    int p = tid >> 1, k = tid & 1;
    lpbuf[p][k] = last_pos[(scn*NP+p)*2+k];
    rpbuf[p][k] = last_pos_rel[(scn*NP+p)*2+k];
    Whp[p][k]   = W_hp[tid];
  }
  if (tid < 2) bhp[tid] = b_hp[tid];
  if (tid < 2*GH) {   // folded Wp1 = W_pse@W1[:16], c1 = b_pse@W1[:16]
    int m = tid / GH, d = tid % GH;
    const float* W1 = m ? W1b : W1a;
    float s0 = 0.f, s1 = 0.f, sc1 = 0.f;
    for (int e = 0; e < ED; e++) {
      float w = W1[e*GH + d];
      s0  += W_pse[e]    * w;
      s1  += W_pse[ED+e] * w;
      sc1 += b_pse[e]    * w;
    }
    Wp1[m][0][d] = s0; Wp1[m][1][d] = s1; c1l[m][d] = sc1;
  }
  for (int r = 0; r < 3; r++) {
    int u = tid + 512*r;
    if (u < 2*GH*GO) {
      int m = u/(GH*GO), rest = u%(GH*GO);
      W2l[m][rest/GO][rest%GO] = (m ? W2b : W2a)[rest];
    }
  }
  __syncthreads();

  // ---------------- time steps ----------------
  for (int t = 0; t < TT; t++) {
    // P1a-G: gates[p][myrow] for 8 peds, Whh from registers
    {
      float rG[8];
      #pragma unroll
      for (int pp2 = 0; pp2 < 8; pp2++) {
        int p = pq*8 + pp2;
        float acc = fmaf(rpbuf[p][0], wf0, fmaf(rpbuf[p][1], wf1, bfr));
        #pragma unroll
        for (int c = 0; c < 8; c++) {
          float4 h4 = *(const float4*)&hbuf[p][c*4];
          acc = fmaf(h4.x, wrow[c*4+0], acc);
          acc = fmaf(h4.y, wrow[c*4+1], acc);
          acc = fmaf(h4.z, wrow[c*4+2], acc);
          acc = fmaf(h4.w, wrow[c*4+3], acc);
        }
        rG[pp2] = acc;
      }
      #pragma unroll
      for (int pp2 = 0; pp2 < 8; pp2++) uni[(pq*8+pp2)*128 + myrow] = rG[pp2];
    }
    __syncthreads();

    // P1a-combine: activations, c/h2 update; fused rel_pos reduction + output store
    {
      #pragma unroll
      for (int r = 0; r < 2; r++) {
        int p = grp + 16*r, n = lane;
        float gi_ = uni[p*128 +       n];
        float gf_ = uni[p*128 +  32 + n];
        float gg_ = uni[p*128 +  64 + n];
        float go_ = uni[p*128 +  96 + n];
        float c2 = sigm(gf_)*creg[r] + sigm(gi_)*tanhfast(gg_);
        creg[r] = c2;
        float h2 = sigm(go_)*tanhfast(c2);
        h2buf[p][n] = h2;
        float r0 = h2 * Whp[n][0];
        float r1 = h2 * Whp[n][1];
        #pragma unroll
        for (int off = 1; off < 32; off <<= 1) {
          r0 += __shfl_xor(r0, off, 32);
          r1 += __shfl_xor(r1, off, 32);
        }
        r0 += bhp[0]; r1 += bhp[1];
        if (n == 0) {
          out[t*NB*2 + (scn*NP+p)*2 + 0] = r0;
          out[t*NB*2 + (scn*NP+p)*2 + 1] = r1;
          rpbuf[p][0] = r0;  rpbuf[p][1] = r1;
          lpbuf[p][0] += r0; lpbuf[p][1] += r1;
        }
      }
    }
    __syncthreads();

    // -------- pool: same(m=0) then diff(m=1), reusing a1/e1/GS1 --------
    for (int m = 0; m < 2; m++) {
      const float* W1 = m ? W1b : W1a;
      // P2: a1[j][d], e1[j][d]; GS via in-phase shfl over the 32-j group
      for (int r = 0; r < 5; r++) {
        int u = tid + 512*r;
        if (u < NP*GH) {
          int d = u >> 5, j = u & 31;
          float pp_ = fmaf(lpbuf[j][0], Wp1[m][0][d], lpbuf[j][1]*Wp1[m][1][d]);
          float av = pp_;
          #pragma unroll
          for (int hk = 0; hk < HD; hk++)
            av = fmaf(h2buf[j][hk], W1[(ED+hk)*GH + d], av);
          a1[j*76 + d] = av;
          e1[j*76 + d] = c1l[m][d] - pp_;
          int gj = gl[j];
          float tot = av;
          float s1 = (gj==1)?av:0.f, s2=(gj==2)?av:0.f, s3=(gj==3)?av:0.f, s4=(gj==4)?av:0.f;
          #pragma unroll
          for (int off = 1; off < 32; off <<= 1) {
            tot += __shfl_xor(tot, off, 32);
            s1  += __shfl_xor(s1,  off, 32);
            s2  += __shfl_xor(s2,  off, 32);
            s3  += __shfl_xor(s3,  off, 32);
            s4  += __shfl_xor(s4,  off, 32);
          }
          if (j < 5) {
            float v;
            if (m == 0) v = (j==0)?tot:((j==1)?s1:((j==2)?s2:((j==3)?s3:s4)));
            else        v = (j==0)?tot:((j==1)?tot-s1:((j==2)?tot-s2:((j==3)?tot-s3:tot-s4)));
            GS1[j][d] = v;
          }
        }
      }
      __syncthreads();

      // P3: pool for this m. lane=j; tasks i=grp (r=0) and i=grp+16 (r=1) share a1[j] reads
      {
        const int j = lane;
        int   I2[2] = {grp, grp + 16};
        const float *P0[2], *P1[2];
        float C0[2], C1[2];
        bool  MIJ[2], DIAG[2];
        v2f qv[2][4];
        #pragma unroll
        for (int r = 0; r < 2; r++) {
          int i = I2[r];
          unsigned bmv = bm[m][i];
          bool mij = (bmv >> j) & 1u;
          bool diag = (j == i);
          int gi = gl[i];
          float in_ = invn[m][i];
          const float *p0, *p1; float c0, c1c;
          if (diag) {
            if (m == 0) { p0 = gi ? &GS1[gi][0] : (a1 + i*76); c0 = in_; p1 = a1 + i*76; c1c = 0.f; }
            else        { p0 = &GS1[gi][0];                    c0 = in_; p1 = a1 + i*76; c1c = gi ? in_ : 0.f; }
          } else if (mij) { p0 = a1 + j*76; c0 = 0.5f; p1 = a1 + i*76; c1c = 0.5f; }
          else            { p0 = a1 + j*76; c0 = 1.0f; p1 = a1 + j*76; c1c = 0.f; }
          P0[r]=p0; P1[r]=p1; C0[r]=c0; C1[r]=c1c; MIJ[r]=mij; DIAG[r]=diag;
          #pragma unroll
          for (int h = 0; h < 4; h++) qv[r][h] = (v2f){0.f, 0.f};
        }
        const float* ej0 = e1 + I2[0]*76;
        const float* ej1 = e1 + I2[1]*76;
        for (int d4 = 0; d4 < GH/4; d4++) {
          float4 vaS = *(const float4*)(a1 + j*76 + d4*4);
          float4 va0 = vaS, va1 = vaS;
          if (DIAG[0]) va0 = *(const float4*)(P0[0] + d4*4);
          if (DIAG[1]) va1 = *(const float4*)(P0[1] + d4*4);
          float4 vb0 = *(const float4*)(P1[0] + d4*4);
          float4 vb1 = *(const float4*)(P1[1] + d4*4);
          float4 ve0 = *(const float4*)(ej0 + d4*4);
          float4 ve1 = *(const float4*)(ej1 + d4*4);
          float tv0[4], tv1[4];
          tv0[0] = fmaxf(fmaf(C0[0], va0.x, fmaf(C1[0], vb0.x, ve0.x)), 0.f);
          tv0[1] = fmaxf(fmaf(C0[0], va0.y, fmaf(C1[0], vb0.y, ve0.y)), 0.f);
          tv0[2] = fmaxf(fmaf(C0[0], va0.z, fmaf(C1[0], vb0.z, ve0.z)), 0.f);
          tv0[3] = fmaxf(fmaf(C0[0], va0.w, fmaf(C1[0], vb0.w, ve0.w)), 0.f);
          tv1[0] = fmaxf(fmaf(C0[1], va1.x, fmaf(C1[1], vb1.x, ve1.x)), 0.f);
          tv1[1] = fmaxf(fmaf(C0[1], va1.y, fmaf(C1[1], vb1.y, ve1.y)), 0.f);
          tv1[2] = fmaxf(fmaf(C0[1], va1.z, fmaf(C1[1], vb1.z, ve1.z)), 0.f);
          tv1[3] = fmaxf(fmaf(C0[1], va1.w, fmaf(C1[1], vb1.w, ve1.w)), 0.f);
          #pragma unroll
          for (int k = 0; k < 4; k++) {
            const v2f* w2p = (const v2f*)&W2l[m][d4*4+k][0];
            v2f wA = w2p[0], wB = w2p[1], wC = w2p[2], wD = w2p[3];
            v2f t0 = {tv0[k], tv0[k]};
            qv[0][0] += t0*wA; qv[0][1] += t0*wB; qv[0][2] += t0*wC; qv[0][3] += t0*wD;
            v2f t1 = {tv1[k], tv1[k]};
            qv[1][0] += t1*wA; qv[1][1] += t1*wB; qv[1][2] += t1*wC; qv[1][3] += t1*wD;
          }
        }
        #pragma unroll
        for (int r = 0; r < 2; r++) {
          float q[8];
          #pragma unroll
          for (int h = 0; h < 4; h++) { q[2*h] = qv[r][h][0]; q[2*h+1] = qv[r][h][1]; }
          float sq[8];
          #pragma unroll
          for (int o = 0; o < 8; o++) sq[o] = MIJ[r] ? q[o] : 0.f;
          #pragma unroll
          for (int off = 1; off < 32; off <<= 1) {
            #pragma unroll
            for (int o = 0; o < 8; o++) sq[o] += __shfl_xor(sq[o], off, 32);
          }
          float qd[8];
          #pragma unroll
          for (int o = 0; o < 8; o++) qd[o] = __shfl(q[o], I2[r], 32);
          float in_ = invn[m][I2[r]];
          float F[8];
          if (DIAG[r]) {
            #pragma unroll
            for (int o = 0; o < 8; o++) F[o] = fmaxf(sq[o]*in_, 0.f);
          } else {
            float scl = MIJ[r] ? 0.5f : 1.0f;
            #pragma unroll
            for (int o = 0; o < 8; o++)
              F[o] = fmaxf((q[o] + (MIJ[r] ? qd[o] : 0.f))*scl, 0.f);
          }
          #pragma unroll
          for (int off = 1; off < 32; off <<= 1) {
            #pragma unroll
            for (int o = 0; o < 8; o++) F[o] = fmaxf(F[o], __shfl_xor(F[o], off, 32));
          }
          if (j == 0) {
            #pragma unroll
            for (int o = 0; o < 8; o++) phbuf[I2[r]][m*GO + o] = F[o];
          }
        }
      }
      __syncthreads();
    }

    // P4: mlp (48 -> 64 -> 32, relu both). 32 lanes per ped; writes new h.
    {
      int u = lane;
      #pragma unroll
      for (int r = 0; r < 2; r++) {
        int p = grp + 16*r;
        float m1lo = b_m1[u];
        float m1hi = b_m1[32 + u];
        for (int k = 0; k < HD; k++) {
          float hv = h2buf[p][k];
          m1lo = fmaf(hv, W_m1[k*MD + u],      m1lo);
          m1hi = fmaf(hv, W_m1[k*MD + 32 + u], m1hi);
        }
        for (int k = 0; k < 2*GO; k++) {
          float pv = phbuf[p][k];
          m1lo = fmaf(pv, W_m1[(HD+k)*MD + u],      m1lo);
          m1hi = fmaf(pv, W_m1[(HD+k)*MD + 32 + u], m1hi);
        }
        m1lo = fmaxf(m1lo, 0.f); m1hi = fmaxf(m1hi, 0.f);
        float acc = b_m2[u];
        for (int k = 0; k < 32; k++)
          acc = fmaf(__shfl(m1lo, k, 32), W_m2[k*HD + u], acc);
        for (int k = 0; k < 32; k++)
          acc = fmaf(__shfl(m1hi, k, 32), W_m2[(32+k)*HD + u], acc);
        hbuf[p][u] = fmaxf(acc, 0.f);
      }
    }
    __syncthreads();
  }
}

extern "C" void kernel_launch(void* const* d_in, const int* in_sizes, int n_in,
                              void* d_out, int out_size, void* d_ws, size_t ws_size,
                              hipStream_t stream) {
  (void)in_sizes; (void)n_in; (void)out_size; (void)d_ws; (void)ws_size;
  const float* last_pos     = (const float*)d_in[0];
  const float* last_pos_rel = (const float*)d_in[1];
  const float* hh           = (const float*)d_in[2];
  const float* ch           = (const float*)d_in[3];
  // d_in[4] = seq_start_end (uniform scenes; unused)
  const int*  eg            = (const int*) d_in[5];
  const float* W_se  = (const float*)d_in[6];
  const float* b_se  = (const float*)d_in[7];
  const float* Wih   = (const float*)d_in[8];
  const float* Whh   = (const float*)d_in[9];
  const float* bih   = (const float*)d_in[10];
  const float* bhh   = (const float*)d_in[11];
  const float* W_hp  = (const float*)d_in[12];
  const float* b_hp  = (const float*)d_in[13];
  const float* W_pse = (const float*)d_in[14];
  const float* b_pse = (const float*)d_in[15];
  const float* W1a   = (const float*)d_in[16];
  const float* W2a   = (const float*)d_in[17];
  const float* W1b   = (const float*)d_in[18];
  const float* W2b   = (const float*)d_in[19];
  const float* W_m1  = (const float*)d_in[20];
  const float* b_m1  = (const float*)d_in[21];
  const float* W_m2  = (const float*)d_in[22];
  const float* b_m2  = (const float*)d_in[23];
  float* out = (float*)d_out;

  decoder_kernel<<<NS, 512, 0, stream>>>(
      last_pos, last_pos_rel, hh, ch, eg,
      W_se, b_se, Wih, Whh, bih, bhh, W_hp, b_hp, W_pse, b_pse,
      W1a, W2a, W1b, W2b, W_m1, b_m1, W_m2, b_m2, out);
}

// Round 4
// 375.917 us; speedup vs baseline: 2.0236x; 1.9279x over previous
//
#include <hip/hip_runtime.h>

#define NS 128
#define NP 32
#define HD 32
#define ED 16
#define GH 72
#define GO 8
#define MD 64
#define TT 8
#define NB (NS*NP)

typedef float v2f __attribute__((ext_vector_type(2)));

__device__ __forceinline__ float sigm(float x){ return 1.0f/(1.0f+__expf(-x)); }
__device__ __forceinline__ float tanhfast(float x){ return 1.0f - 2.0f/(__expf(2.0f*x)+1.0f); }
__device__ __forceinline__ unsigned rne16(float f){
  unsigned u = __float_as_uint(f);
  u += 0x7fffu + ((u>>16)&1u);
  return u>>16;
}
__device__ __forceinline__ float lo16(unsigned v){ return __uint_as_float(v<<16); }
__device__ __forceinline__ float hi16(unsigned v){ return __uint_as_float(v & 0xffff0000u); }

__global__ __launch_bounds__(1024, 1) void decoder_kernel(
    const float* __restrict__ last_pos, const float* __restrict__ last_pos_rel,
    const float* __restrict__ hh, const float* __restrict__ ch,
    const int*  __restrict__ eg,
    const float* __restrict__ W_se, const float* __restrict__ b_se,
    const float* __restrict__ Wih, const float* __restrict__ Whh,
    const float* __restrict__ bih, const float* __restrict__ bhh,
    const float* __restrict__ W_hp, const float* __restrict__ b_hp,
    const float* __restrict__ W_pse, const float* __restrict__ b_pse,
    const float* __restrict__ W1a, const float* __restrict__ W2a,
    const float* __restrict__ W1b, const float* __restrict__ W2b,
    const float* __restrict__ W_m1, const float* __restrict__ b_m1,
    const float* __restrict__ W_m2, const float* __restrict__ b_m2,
    float* __restrict__ out)
{
  const int tid   = threadIdx.x;
  const int scn   = blockIdx.x;
  const int lane  = tid & 31;
  const int grp32 = tid >> 5;      // 0..31

  // uni overlays: G[32][128] gate staging (16 KB) <-> a[2][32][76] (19.4 KB)
  __shared__ __align__(16) float uni[4864];
  __shared__ __align__(16) unsigned W1p[2][16][GH];  // bf16 pairs (hk, hk+1)
  __shared__ __align__(16) float W2l[2][GH][GO];
  __shared__ __align__(16) float Wp1[2][2][GH];
  __shared__ __align__(16) float c1l[2][GH];
  __shared__ __align__(16) float hbuf[NP][HD];
  __shared__ __align__(16) float h2buf[NP][36];      // 16B-aligned rows
  __shared__ __align__(16) float GS[2][5][GH];
  __shared__ __align__(16) float phbuf[NP][16];
  __shared__ __align__(16) unsigned Wm1p[48][32];    // bf16 pairs (u, u+32)
  __shared__ __align__(16) unsigned Wm2p[32][32];    // bf16 pairs (k, k+32)
  __shared__ float lpbuf[NP][2], rpbuf[NP][2], Whp[HD][2];
  __shared__ float bm1l[MD], bm2l[HD], bhp2[2];
  __shared__ unsigned bm[2][NP];
  __shared__ float invn[2][NP];
  __shared__ int gl[NP];

  // ---------- persistent per-thread LSTM row weights (global read ONCE) ----------
  const int myrow = tid & 127;     // gate row 0..127
  const int pq4   = tid >> 7;      // 0..7 -> 4 peds each
  float wrow[HD];
  #pragma unroll
  for (int c = 0; c < HD/4; c++) {
    float4 w = *(const float4*)(Whh + myrow*HD + c*4);
    wrow[c*4+0]=w.x; wrow[c*4+1]=w.y; wrow[c*4+2]=w.z; wrow[c*4+3]=w.w;
  }
  float wf0 = 0.f, wf1 = 0.f, bfr = bih[myrow] + bhh[myrow];
  #pragma unroll
  for (int e = 0; e < ED; e++) {
    float wv = Wih[myrow*ED + e];
    wf0 = fmaf(W_se[e],    wv, wf0);
    wf1 = fmaf(W_se[ED+e], wv, wf1);
    bfr = fmaf(b_se[e],    wv, bfr);
  }

  // ---------- persistent cell state: thread (grp32, lane) owns cell (p=grp32, n=lane) ----
  float creg = ch[(scn*NP + grp32)*HD + lane];
  hbuf[grp32][lane] = hh[(scn*NP + grp32)*HD + lane];

  // ---------- setup ----------
  if (tid < NP) {
    int gi = eg[scn*NP + tid];
    gl[tid] = gi;
    unsigned sm = 0;
    for (int j = 0; j < NP; j++) {
      int gj = eg[scn*NP + j];
      bool sj = (j == tid) || (gi == gj && gi != 0);
      sm |= ((unsigned)sj) << j;
    }
    unsigned dm = (~sm) | (1u << tid);
    bm[0][tid] = sm; bm[1][tid] = dm;
    invn[0][tid] = 1.0f/(float)__popc(sm);
    invn[1][tid] = 1.0f/(float)__popc(dm);
  }
  if (tid < 64) {
    int p = tid >> 1, k = tid & 1;
    lpbuf[p][k] = last_pos[(scn*NP+p)*2+k];
    rpbuf[p][k] = last_pos_rel[(scn*NP+p)*2+k];
    Whp[p][k]   = W_hp[tid];
    bm1l[tid]   = b_m1[tid];
  }
  if (tid < 32) bm2l[tid] = b_m2[tid];
  if (tid < 2)  bhp2[tid] = b_hp[tid];
  if (tid < 2*GH) {   // folded Wp1 = W_pse@W1[:16], c1 = b_pse@W1[:16]
    int m = tid / GH, d = tid % GH;
    const float* W1 = m ? W1b : W1a;
    float s0 = 0.f, s1 = 0.f, sc1 = 0.f;
    for (int e = 0; e < ED; e++) {
      float w = W1[e*GH + d];
      s0  += W_pse[e]    * w;
      s1  += W_pse[ED+e] * w;
      sc1 += b_pse[e]    * w;
    }
    Wp1[m][0][d] = s0; Wp1[m][1][d] = s1; c1l[m][d] = sc1;
  }
  {  // W2l fp32 (1152)
    int u = tid;
    if (u < 2*GH*GO) {
      int m = u/(GH*GO), rest = u%(GH*GO);
      W2l[m][rest/GO][rest%GO] = (m ? W2b : W2a)[rest];
    }
    if (tid < 128) {
      int u2 = tid + 1024;
      int m = u2/(GH*GO), rest = u2%(GH*GO);
      W2l[m][rest/GO][rest%GO] = (m ? W2b : W2a)[rest];
    }
  }
  #pragma unroll
  for (int r = 0; r < 3; r++) {   // W1p packed bf16 (2304)
    int u = tid + 1024*r;
    if (u < 2304) {
      int m = u/1152, rest = u%1152, k2 = rest/GH, d = rest%GH;
      const float* W1 = m ? W1b : W1a;
      unsigned lo = rne16(W1[(ED+2*k2  )*GH + d]);
      unsigned hi = rne16(W1[(ED+2*k2+1)*GH + d]);
      W1p[m][k2][d] = lo | (hi << 16);
    }
  }
  #pragma unroll
  for (int r = 0; r < 2; r++) {   // Wm1p packed bf16 (1536)
    int u = tid + 1024*r;
    if (u < 1536) {
      int k = u >> 5, uu = u & 31;
      unsigned lo = rne16(W_m1[k*MD + uu]);
      unsigned hi = rne16(W_m1[k*MD + 32 + uu]);
      Wm1p[k][uu] = lo | (hi << 16);
    }
  }
  {  // Wm2p packed bf16 (1024)
    int k = tid >> 5, uu = tid & 31;
    unsigned lo = rne16(W_m2[k*HD + uu]);
    unsigned hi = rne16(W_m2[(k+32)*HD + uu]);
    Wm2p[k][uu] = lo | (hi << 16);
  }
  __syncthreads();

  // ---------------- time steps ----------------
  for (int t = 0; t < TT; t++) {
    // P1a-G: gates[p][myrow] for 4 peds, Whh from registers
    {
      float rG[4];
      #pragma unroll
      for (int pp2 = 0; pp2 < 4; pp2++) {
        int p = pq4*4 + pp2;
        float acc = fmaf(rpbuf[p][0], wf0, fmaf(rpbuf[p][1], wf1, bfr));
        #pragma unroll
        for (int c = 0; c < 8; c++) {
          float4 h4 = *(const float4*)&hbuf[p][c*4];
          acc = fmaf(h4.x, wrow[c*4+0], acc);
          acc = fmaf(h4.y, wrow[c*4+1], acc);
          acc = fmaf(h4.z, wrow[c*4+2], acc);
          acc = fmaf(h4.w, wrow[c*4+3], acc);
        }
        rG[pp2] = acc;
      }
      #pragma unroll
      for (int pp2 = 0; pp2 < 4; pp2++) uni[(pq4*4+pp2)*128 + myrow] = rG[pp2];
    }
    __syncthreads();

    // P1b: activations, c/h2 update; fused rel_pos reduction + output store
    {
      int p = grp32, n = lane;
      float gi_ = uni[p*128 +       n];
      float gf_ = uni[p*128 +  32 + n];
      float gg_ = uni[p*128 +  64 + n];
      float go_ = uni[p*128 +  96 + n];
      float c2 = sigm(gf_)*creg + sigm(gi_)*tanhfast(gg_);
      creg = c2;
      float h2 = sigm(go_)*tanhfast(c2);
      h2buf[p][n] = h2;
      float r0 = h2 * Whp[n][0];
      float r1 = h2 * Whp[n][1];
      #pragma unroll
      for (int off = 1; off < 32; off <<= 1) {
        r0 += __shfl_xor(r0, off, 32);
        r1 += __shfl_xor(r1, off, 32);
      }
      r0 += bhp2[0]; r1 += bhp2[1];
      if (n == 0) {
        out[t*NB*2 + (scn*NP+p)*2 + 0] = r0;
        out[t*NB*2 + (scn*NP+p)*2 + 1] = r1;
        rpbuf[p][0] = r0;  rpbuf[p][1] = r1;
        lpbuf[p][0] += r0; lpbuf[p][1] += r1;
      }
    }
    __syncthreads();

    // P2: a[m][j][d] for BOTH m + GS group sums. j = lane invariant across passes.
    {
      const int j = lane;
      float lpj0 = lpbuf[j][0], lpj1 = lpbuf[j][1];
      float h2row[HD];
      #pragma unroll
      for (int c = 0; c < 8; c++) {
        float4 v = *(const float4*)&h2buf[j][c*4];
        h2row[c*4+0]=v.x; h2row[c*4+1]=v.y; h2row[c*4+2]=v.z; h2row[c*4+3]=v.w;
      }
      #pragma unroll
      for (int r = 0; r < 5; r++) {
        int rest = grp32 + 32*r;       // uniform per 32-group
        if (rest < 144) {
          int m = rest >= 72 ? 1 : 0;
          int d = rest - 72*m;
          float pp_ = fmaf(lpj0, Wp1[m][0][d], lpj1*Wp1[m][1][d]);
          float av = pp_;
          #pragma unroll
          for (int k2 = 0; k2 < 16; k2++) {
            unsigned v = W1p[m][k2][d];
            av = fmaf(h2row[2*k2  ], lo16(v), av);
            av = fmaf(h2row[2*k2+1], hi16(v), av);
          }
          uni[m*2432 + j*76 + d] = av;
          int gj = gl[j];
          float tot = av;
          float s1 = (gj==1)?av:0.f, s2=(gj==2)?av:0.f, s3=(gj==3)?av:0.f, s4=(gj==4)?av:0.f;
          #pragma unroll
          for (int off = 1; off < 32; off <<= 1) {
            tot += __shfl_xor(tot, off, 32);
            s1  += __shfl_xor(s1,  off, 32);
            s2  += __shfl_xor(s2,  off, 32);
            s3  += __shfl_xor(s3,  off, 32);
            s4  += __shfl_xor(s4,  off, 32);
          }
          if (j < 5) {
            float v2;
            if (m == 0) v2 = (j==0)?tot:((j==1)?s1:((j==2)?s2:((j==3)?s3:s4)));
            else        v2 = (j==0)?tot:((j==1)?tot-s1:((j==2)?tot-s2:((j==3)?tot-s3:tot-s4)));
            GS[m][j][d] = v2;
          }
        }
      }
    }
    __syncthreads();

    // P3: pool. m = wave>>3; thread handles (m, i=sub) and (m, i=sub+16); j = lane.
    {
      const int j   = lane;
      const int m   = tid >> 9;
      const int sub = (tid >> 5) & 15;
      const float* am = uni + m*2432;
      int   I2[2] = {sub, sub + 16};
      const float *P0[2], *P1[2];
      float C0[2], C1[2], NL0[2], NL1[2];
      bool  MIJ[2], DIAG[2];
      v2f qv[2][4];
      #pragma unroll
      for (int r = 0; r < 2; r++) {
        int i = I2[r];
        unsigned bmv = bm[m][i];
        bool mij = (bmv >> j) & 1u;
        bool diag = (j == i);
        int gi = gl[i];
        float in_ = invn[m][i];
        const float *p0, *p1; float c0, c1c;
        if (diag) {
          if (m == 0) { p0 = gi ? &GS[0][gi][0] : (am + i*76); c0 = in_; p1 = am + i*76; c1c = 0.f; }
          else        { p0 = &GS[1][gi][0];                    c0 = in_; p1 = am + i*76; c1c = gi ? in_ : 0.f; }
        } else if (mij) { p0 = am + j*76; c0 = 0.5f; p1 = am + i*76; c1c = 0.5f; }
        else            { p0 = am + j*76; c0 = 1.0f; p1 = am + j*76; c1c = 0.f; }
        P0[r]=p0; P1[r]=p1; C0[r]=c0; C1[r]=c1c; MIJ[r]=mij; DIAG[r]=diag;
        NL0[r] = -lpbuf[i][0]; NL1[r] = -lpbuf[i][1];
        #pragma unroll
        for (int h = 0; h < 4; h++) qv[r][h] = (v2f){0.f, 0.f};
      }
      for (int d4 = 0; d4 < GH/4; d4++) {
        float4 c14 = *(const float4*)&c1l[m][d4*4];
        float4 w04 = *(const float4*)&Wp1[m][0][d4*4];
        float4 w14 = *(const float4*)&Wp1[m][1][d4*4];
        float4 vaS = *(const float4*)(am + j*76 + d4*4);
        float4 va0 = vaS, va1 = vaS;
        if (DIAG[0]) va0 = *(const float4*)(P0[0] + d4*4);
        if (DIAG[1]) va1 = *(const float4*)(P0[1] + d4*4);
        float4 vb0 = *(const float4*)(P1[0] + d4*4);
        float4 vb1 = *(const float4*)(P1[1] + d4*4);
        // e_i[d] = c1l - lp_i0*Wp1_0 - lp_i1*Wp1_1 (recomputed, rank-2)
        float e0x = fmaf(NL1[0], w14.x, fmaf(NL0[0], w04.x, c14.x));
        float e0y = fmaf(NL1[0], w14.y, fmaf(NL0[0], w04.y, c14.y));
        float e0z = fmaf(NL1[0], w14.z, fmaf(NL0[0], w04.z, c14.z));
        float e0w = fmaf(NL1[0], w14.w, fmaf(NL0[0], w04.w, c14.w));
        float e1x = fmaf(NL1[1], w14.x, fmaf(NL0[1], w04.x, c14.x));
        float e1y = fmaf(NL1[1], w14.y, fmaf(NL0[1], w04.y, c14.y));
        float e1z = fmaf(NL1[1], w14.z, fmaf(NL0[1], w04.z, c14.z));
        float e1w = fmaf(NL1[1], w14.w, fmaf(NL0[1], w04.w, c14.w));
        float tv0[4], tv1[4];
        tv0[0] = fmaxf(fmaf(C0[0], va0.x, fmaf(C1[0], vb0.x, e0x)), 0.f);
        tv0[1] = fmaxf(fmaf(C0[0], va0.y, fmaf(C1[0], vb0.y, e0y)), 0.f);
        tv0[2] = fmaxf(fmaf(C0[0], va0.z, fmaf(C1[0], vb0.z, e0z)), 0.f);
        tv0[3] = fmaxf(fmaf(C0[0], va0.w, fmaf(C1[0], vb0.w, e0w)), 0.f);
        tv1[0] = fmaxf(fmaf(C0[1], va1.x, fmaf(C1[1], vb1.x, e1x)), 0.f);
        tv1[1] = fmaxf(fmaf(C0[1], va1.y, fmaf(C1[1], vb1.y, e1y)), 0.f);
        tv1[2] = fmaxf(fmaf(C0[1], va1.z, fmaf(C1[1], vb1.z, e1z)), 0.f);
        tv1[3] = fmaxf(fmaf(C0[1], va1.w, fmaf(C1[1], vb1.w, e1w)), 0.f);
        #pragma unroll
        for (int k = 0; k < 4; k++) {
          const v2f* w2p = (const v2f*)&W2l[m][d4*4+k][0];
          v2f wA = w2p[0], wB = w2p[1], wC = w2p[2], wD = w2p[3];
          v2f t0 = {tv0[k], tv0[k]};
          qv[0][0] += t0*wA; qv[0][1] += t0*wB; qv[0][2] += t0*wC; qv[0][3] += t0*wD;
          v2f t1 = {tv1[k], tv1[k]};
          qv[1][0] += t1*wA; qv[1][1] += t1*wB; qv[1][2] += t1*wC; qv[1][3] += t1*wD;
        }
      }
      #pragma unroll
      for (int r = 0; r < 2; r++) {
        float q[8];
        #pragma unroll
        for (int h = 0; h < 4; h++) { q[2*h] = qv[r][h][0]; q[2*h+1] = qv[r][h][1]; }
        float sq[8];
        #pragma unroll
        for (int o = 0; o < 8; o++) sq[o] = MIJ[r] ? q[o] : 0.f;
        #pragma unroll
        for (int off = 1; off < 32; off <<= 1) {
          #pragma unroll
          for (int o = 0; o < 8; o++) sq[o] += __shfl_xor(sq[o], off, 32);
        }
        float qd[8];
        #pragma unroll
        for (int o = 0; o < 8; o++) qd[o] = __shfl(q[o], I2[r], 32);
        float in_ = invn[m][I2[r]];
        float F[8];
        if (DIAG[r]) {
          #pragma unroll
          for (int o = 0; o < 8; o++) F[o] = fmaxf(sq[o]*in_, 0.f);
        } else {
          float scl = MIJ[r] ? 0.5f : 1.0f;
          #pragma unroll
          for (int o = 0; o < 8; o++)
            F[o] = fmaxf((q[o] + (MIJ[r] ? qd[o] : 0.f))*scl, 0.f);
        }
        #pragma unroll
        for (int off = 1; off < 32; off <<= 1) {
          #pragma unroll
          for (int o = 0; o < 8; o++) F[o] = fmaxf(F[o], __shfl_xor(F[o], off, 32));
        }
        if (j == 0) {
          #pragma unroll
          for (int o = 0; o < 8; o++) phbuf[I2[r]][m*GO + o] = F[o];
        }
      }
    }
    __syncthreads();

    // P4: mlp (48 -> 64 -> 32, relu both). 32 lanes per ped, single pass.
    {
      int p = grp32, u = lane;
      float in48[48];
      #pragma unroll
      for (int c = 0; c < 8; c++) {
        float4 v = *(const float4*)&h2buf[p][c*4];
        in48[c*4+0]=v.x; in48[c*4+1]=v.y; in48[c*4+2]=v.z; in48[c*4+3]=v.w;
      }
      #pragma unroll
      for (int c = 0; c < 4; c++) {
        float4 v = *(const float4*)&phbuf[p][c*4];
        in48[32+c*4+0]=v.x; in48[32+c*4+1]=v.y; in48[32+c*4+2]=v.z; in48[32+c*4+3]=v.w;
      }
      float m1lo = bm1l[u], m1hi = bm1l[32 + u];
      #pragma unroll
      for (int k = 0; k < 48; k++) {
        unsigned v = Wm1p[k][u];
        m1lo = fmaf(in48[k], lo16(v), m1lo);
        m1hi = fmaf(in48[k], hi16(v), m1hi);
      }
      m1lo = fmaxf(m1lo, 0.f); m1hi = fmaxf(m1hi, 0.f);
      float acc = bm2l[u];
      #pragma unroll
      for (int k = 0; k < 32; k++) {
        unsigned v = Wm2p[k][u];
        acc = fmaf(__shfl(m1lo, k, 32), lo16(v), acc);
        acc = fmaf(__shfl(m1hi, k, 32), hi16(v), acc);
      }
      hbuf[p][u] = fmaxf(acc, 0.f);
    }
    __syncthreads();
  }
}

extern "C" void kernel_launch(void* const* d_in, const int* in_sizes, int n_in,
                              void* d_out, int out_size, void* d_ws, size_t ws_size,
                              hipStream_t stream) {
  (void)in_sizes; (void)n_in; (void)out_size; (void)d_ws; (void)ws_size;
  const float* last_pos     = (const float*)d_in[0];
  const float* last_pos_rel = (const float*)d_in[1];
  const float* hh           = (const float*)d_in[2];
  const float* ch           = (const float*)d_in[3];
  // d_in[4] = seq_start_end (uniform scenes; unused)
  const int*  eg            = (const int*) d_in[5];
  const float* W_se  = (const float*)d_in[6];
  const float* b_se  = (const float*)d_in[7];
  const float* Wih   = (const float*)d_in[8];
  const float* Whh   = (const float*)d_in[9];
  const float* bih   = (const float*)d_in[10];
  const float* bhh   = (const float*)d_in[11];
  const float* W_hp  = (const float*)d_in[12];
  const float* b_hp  = (const float*)d_in[13];
  const float* W_pse = (const float*)d_in[14];
  const float* b_pse = (const float*)d_in[15];
  const float* W1a   = (const float*)d_in[16];
  const float* W2a   = (const float*)d_in[17];
  const float* W1b   = (const float*)d_in[18];
  const float* W2b   = (const float*)d_in[19];
  const float* W_m1  = (const float*)d_in[20];
  const float* b_m1  = (const float*)d_in[21];
  const float* W_m2  = (const float*)d_in[22];
  const float* b_m2  = (const float*)d_in[23];
  float* out = (float*)d_out;

  decoder_kernel<<<NS, 1024, 0, stream>>>(
      last_pos, last_pos_rel, hh, ch, eg,
      W_se, b_se, Wih, Whh, bih, bhh, W_hp, b_hp, W_pse, b_pse,
      W1a, W2a, W1b, W2b, W_m1, b_m1, W_m2, b_m2, out);
}

// Round 6
// 300.768 us; speedup vs baseline: 2.5292x; 1.2499x over previous
//
#include <hip/hip_runtime.h>

#define NS 128
#define NP 32
#define HD 32
#define ED 16
#define GH 72
#define GO 8
#define MD 64
#define TT 8
#define NB (NS*NP)

#define SLOT 272   // floats per slot: 256 data + flag + pad
// 256 blocks x 2 parity slots
#define WS_NEED (256*2*SLOT*4)

typedef float v2f __attribute__((ext_vector_type(2)));

__device__ __forceinline__ float sigm(float x){ return 1.0f/(1.0f+__expf(-x)); }
__device__ __forceinline__ float tanhfast(float x){ return 1.0f - 2.0f/(__expf(2.0f*x)+1.0f); }
__device__ __forceinline__ unsigned rne16(float f){
  unsigned u = __float_as_uint(f);
  u += 0x7fffu + ((u>>16)&1u);
  return u>>16;
}
__device__ __forceinline__ float lo16(unsigned v){ return __uint_as_float(v<<16); }
__device__ __forceinline__ float hi16(unsigned v){ return __uint_as_float(v & 0xffff0000u); }

// ==================== split kernel: 256 blocks, (scene, m) per block ====================
__global__ __launch_bounds__(1024, 1) void decoder_kernel_split(
    const float* __restrict__ last_pos, const float* __restrict__ last_pos_rel,
    const float* __restrict__ hh, const float* __restrict__ ch,
    const int*  __restrict__ eg,
    const float* __restrict__ W_se, const float* __restrict__ b_se,
    const float* __restrict__ Wih, const float* __restrict__ Whh,
    const float* __restrict__ bih, const float* __restrict__ bhh,
    const float* __restrict__ W_hp, const float* __restrict__ b_hp,
    const float* __restrict__ W_pse, const float* __restrict__ b_pse,
    const float* __restrict__ W1a, const float* __restrict__ W2a,
    const float* __restrict__ W1b, const float* __restrict__ W2b,
    const float* __restrict__ W_m1, const float* __restrict__ b_m1,
    const float* __restrict__ W_m2, const float* __restrict__ b_m2,
    float* __restrict__ out, float* __restrict__ ws)
{
  const int tid   = threadIdx.x;
  const int scn   = blockIdx.x >> 1;
  const int myM   = blockIdx.x & 1;
  const int lane  = tid & 31;
  const int grp32 = tid >> 5;      // 0..31

  // uni overlays: G[32][128] gate staging (16 KB) <-> a1[32][76] (9.7 KB)
  __shared__ __align__(16) float uni[4096];
  __shared__ __align__(16) unsigned W1p[16][GH];   // own m, bf16 pairs (hk, hk+1)
  __shared__ __align__(16) float W2l[GH][GO];      // own m
  __shared__ __align__(16) float Wp1[2][GH];       // own m
  __shared__ __align__(16) float c1l[GH];          // own m
  __shared__ __align__(16) float hbuf[NP][HD];
  __shared__ __align__(16) float h2buf[NP][36];
  __shared__ __align__(16) float GS[5][GH];        // own m
  __shared__ __align__(16) float phbuf[NP][16];
  __shared__ __align__(16) unsigned Wm1p[48][32];
  __shared__ __align__(16) unsigned Wm2p[32][32];
  __shared__ float lpbuf[NP][2], rpbuf[NP][2], Whp[HD][2];
  __shared__ float bm1l[MD], bm2l[HD], bhp2[2];
  __shared__ unsigned bm[NP];
  __shared__ float invn[NP];
  __shared__ int gl[NP];

  float* const a1 = uni;   // [32][76]

  const int mybase = (scn*2 + myM)*2;       // slot-pair index (x SLOT)
  const int pbase  = (scn*2 + 1 - myM)*2;

  // ---------- persistent per-thread LSTM row weights (global read ONCE) ----------
  const int myrow = tid & 127;
  const int pq4   = tid >> 7;
  float wrow[HD];
  #pragma unroll
  for (int c = 0; c < HD/4; c++) {
    float4 w = *(const float4*)(Whh + myrow*HD + c*4);
    wrow[c*4+0]=w.x; wrow[c*4+1]=w.y; wrow[c*4+2]=w.z; wrow[c*4+3]=w.w;
  }
  float wf0 = 0.f, wf1 = 0.f, bfr = bih[myrow] + bhh[myrow];
  #pragma unroll
  for (int e = 0; e < ED; e++) {
    float wv = Wih[myrow*ED + e];
    wf0 = fmaf(W_se[e],    wv, wf0);
    wf1 = fmaf(W_se[ED+e], wv, wf1);
    bfr = fmaf(b_se[e],    wv, bfr);
  }

  float creg = ch[(scn*NP + grp32)*HD + lane];
  hbuf[grp32][lane] = hh[(scn*NP + grp32)*HD + lane];

  // ---------- setup ----------
  if (tid < NP) {
    int gi = eg[scn*NP + tid];
    gl[tid] = gi;
    unsigned sm = 0;
    for (int j = 0; j < NP; j++) {
      int gj = eg[scn*NP + j];
      bool sj = (j == tid) || (gi == gj && gi != 0);
      sm |= ((unsigned)sj) << j;
    }
    unsigned mk = myM ? ((~sm) | (1u << tid)) : sm;
    bm[tid] = mk;
    invn[tid] = 1.0f/(float)__popc(mk);
  }
  if (tid < 64) {
    int p = tid >> 1, k = tid & 1;
    lpbuf[p][k] = last_pos[(scn*NP+p)*2+k];
    rpbuf[p][k] = last_pos_rel[(scn*NP+p)*2+k];
    Whp[p][k]   = W_hp[tid];
    bm1l[tid]   = b_m1[tid];
  }
  if (tid < 32) bm2l[tid] = b_m2[tid];
  if (tid < 2)  bhp2[tid] = b_hp[tid];
  const float* W1my = myM ? W1b : W1a;
  if (tid < GH) {   // folded Wp1 = W_pse@W1[:16], c1 = b_pse@W1[:16] (own m)
    int d = tid;
    float s0 = 0.f, s1 = 0.f, sc1 = 0.f;
    for (int e = 0; e < ED; e++) {
      float w = W1my[e*GH + d];
      s0  += W_pse[e]    * w;
      s1  += W_pse[ED+e] * w;
      sc1 += b_pse[e]    * w;
    }
    Wp1[0][d] = s0; Wp1[1][d] = s1; c1l[d] = sc1;
  }
  if (tid < GH*GO) {   // W2 own m, fp32 (576)
    W2l[tid/GO][tid%GO] = (myM ? W2b : W2a)[tid];
  }
  #pragma unroll
  for (int r = 0; r < 2; r++) {  // W1p own m, packed bf16 (1152 > 1024: TWO passes — R5 bug was one)
    int u = tid + 1024*r;
    if (u < 16*GH) {
      int k2 = u/GH, d = u%GH;
      unsigned lo = rne16(W1my[(ED+2*k2  )*GH + d]);
      unsigned hi = rne16(W1my[(ED+2*k2+1)*GH + d]);
      W1p[k2][d] = lo | (hi << 16);
    }
  }
  #pragma unroll
  for (int r = 0; r < 2; r++) {   // Wm1p packed bf16 (1536)
    int u = tid + 1024*r;
    if (u < 1536) {
      int k = u >> 5, uu = u & 31;
      Wm1p[k][uu] = rne16(W_m1[k*MD + uu]) | (rne16(W_m1[k*MD + 32 + uu]) << 16);
    }
  }
  {  // Wm2p packed bf16 (1024)
    int k = tid >> 5, uu = tid & 31;
    Wm2p[k][uu] = rne16(W_m2[k*HD + uu]) | (rne16(W_m2[(k+32)*HD + uu]) << 16);
  }
  __syncthreads();

  // ---------------- time steps ----------------
  for (int t = 0; t < TT; t++) {
    // P1a: gates[p][myrow] for 4 peds (redundant in both blocks; deterministic)
    {
      float rG[4];
      #pragma unroll
      for (int pp2 = 0; pp2 < 4; pp2++) {
        int p = pq4*4 + pp2;
        float acc = fmaf(rpbuf[p][0], wf0, fmaf(rpbuf[p][1], wf1, bfr));
        #pragma unroll
        for (int c = 0; c < 8; c++) {
          float4 h4 = *(const float4*)&hbuf[p][c*4];
          acc = fmaf(h4.x, wrow[c*4+0], acc);
          acc = fmaf(h4.y, wrow[c*4+1], acc);
          acc = fmaf(h4.z, wrow[c*4+2], acc);
          acc = fmaf(h4.w, wrow[c*4+3], acc);
        }
        rG[pp2] = acc;
      }
      #pragma unroll
      for (int pp2 = 0; pp2 < 4; pp2++) uni[(pq4*4+pp2)*128 + myrow] = rG[pp2];
    }
    __syncthreads();

    // P1b: activations, c/h2 update; rel_pos reduction; out store (m=0 block only)
    {
      int p = grp32, n = lane;
      float gi_ = uni[p*128 +       n];
      float gf_ = uni[p*128 +  32 + n];
      float gg_ = uni[p*128 +  64 + n];
      float go_ = uni[p*128 +  96 + n];
      float c2 = sigm(gf_)*creg + sigm(gi_)*tanhfast(gg_);
      creg = c2;
      float h2 = sigm(go_)*tanhfast(c2);
      h2buf[p][n] = h2;
      float r0 = h2 * Whp[n][0];
      float r1 = h2 * Whp[n][1];
      #pragma unroll
      for (int off = 1; off < 32; off <<= 1) {
        r0 += __shfl_xor(r0, off, 32);
        r1 += __shfl_xor(r1, off, 32);
      }
      r0 += bhp2[0]; r1 += bhp2[1];
      if (n == 0) {
        if (myM == 0) {
          out[t*NB*2 + (scn*NP+p)*2 + 0] = r0;
          out[t*NB*2 + (scn*NP+p)*2 + 1] = r1;
        }
        rpbuf[p][0] = r0;  rpbuf[p][1] = r1;
        lpbuf[p][0] += r0; lpbuf[p][1] += r1;
      }
    }
    __syncthreads();

    // P2: a1[j][d] + GS group sums (own m). j = lane invariant across passes.
    {
      const int j = lane;
      float lpj0 = lpbuf[j][0], lpj1 = lpbuf[j][1];
      float h2row[HD];
      #pragma unroll
      for (int c = 0; c < 8; c++) {
        float4 v = *(const float4*)&h2buf[j][c*4];
        h2row[c*4+0]=v.x; h2row[c*4+1]=v.y; h2row[c*4+2]=v.z; h2row[c*4+3]=v.w;
      }
      #pragma unroll
      for (int r = 0; r < 3; r++) {
        int d = grp32 + 32*r;
        if (d < GH) {
          float pp_ = fmaf(lpj0, Wp1[0][d], lpj1*Wp1[1][d]);
          float av = pp_;
          #pragma unroll
          for (int k2 = 0; k2 < 16; k2++) {
            unsigned v = W1p[k2][d];
            av = fmaf(h2row[2*k2  ], lo16(v), av);
            av = fmaf(h2row[2*k2+1], hi16(v), av);
          }
          a1[j*76 + d] = av;
          int gj = gl[j];
          float tot = av;
          float s1 = (gj==1)?av:0.f, s2=(gj==2)?av:0.f, s3=(gj==3)?av:0.f, s4=(gj==4)?av:0.f;
          #pragma unroll
          for (int off = 1; off < 32; off <<= 1) {
            tot += __shfl_xor(tot, off, 32);
            s1  += __shfl_xor(s1,  off, 32);
            s2  += __shfl_xor(s2,  off, 32);
            s3  += __shfl_xor(s3,  off, 32);
            s4  += __shfl_xor(s4,  off, 32);
          }
          if (j < 5) {
            float v2;
            if (myM == 0) v2 = (j==0)?tot:((j==1)?s1:((j==2)?s2:((j==3)?s3:s4)));
            else          v2 = (j==0)?tot:((j==1)?tot-s1:((j==2)?tot-s2:((j==3)?tot-s3:tot-s4)));
            GS[j][d] = v2;
          }
        }
      }
    }
    __syncthreads();

    // P3: pool (own m). One task per thread: i = grp32, j = lane.
    {
      const int j = lane, i = grp32;
      unsigned bmv = bm[i];
      bool mij = (bmv >> j) & 1u;
      bool diag = (j == i);
      int gi = gl[i];
      float in_ = invn[i];
      const float *p0, *p1; float c0, c1c;
      if (diag) {
        if (myM == 0) { p0 = gi ? &GS[gi][0] : (a1 + i*76); c0 = in_; p1 = a1 + i*76; c1c = 0.f; }
        else          { p0 = &GS[gi][0];                    c0 = in_; p1 = a1 + i*76; c1c = gi ? in_ : 0.f; }
      } else if (mij) { p0 = a1 + j*76; c0 = 0.5f; p1 = a1 + i*76; c1c = 0.5f; }
      else            { p0 = a1 + j*76; c0 = 1.0f; p1 = a1 + j*76; c1c = 0.f; }
      float NL0 = -lpbuf[i][0], NL1 = -lpbuf[i][1];
      v2f qv[4];
      #pragma unroll
      for (int h = 0; h < 4; h++) qv[h] = (v2f){0.f, 0.f};
      for (int d4 = 0; d4 < GH/4; d4++) {
        float4 c14 = *(const float4*)&c1l[d4*4];
        float4 w04 = *(const float4*)&Wp1[0][d4*4];
        float4 w14 = *(const float4*)&Wp1[1][d4*4];
        float4 va  = diag ? *(const float4*)(p0 + d4*4)
                          : *(const float4*)(a1 + j*76 + d4*4);
        float4 vb  = *(const float4*)(p1 + d4*4);
        float ex = fmaf(NL1, w14.x, fmaf(NL0, w04.x, c14.x));
        float ey = fmaf(NL1, w14.y, fmaf(NL0, w04.y, c14.y));
        float ez = fmaf(NL1, w14.z, fmaf(NL0, w04.z, c14.z));
        float ew = fmaf(NL1, w14.w, fmaf(NL0, w04.w, c14.w));
        float tv[4];
        tv[0] = fmaxf(fmaf(c0, va.x, fmaf(c1c, vb.x, ex)), 0.f);
        tv[1] = fmaxf(fmaf(c0, va.y, fmaf(c1c, vb.y, ey)), 0.f);
        tv[2] = fmaxf(fmaf(c0, va.z, fmaf(c1c, vb.z, ez)), 0.f);
        tv[3] = fmaxf(fmaf(c0, va.w, fmaf(c1c, vb.w, ew)), 0.f);
        #pragma unroll
        for (int k = 0; k < 4; k++) {
          const v2f* w2p = (const v2f*)&W2l[d4*4+k][0];
          v2f wA = w2p[0], wB = w2p[1], wC = w2p[2], wD = w2p[3];
          v2f tk = {tv[k], tv[k]};
          qv[0] += tk*wA; qv[1] += tk*wB; qv[2] += tk*wC; qv[3] += tk*wD;
        }
      }
      float q[8];
      #pragma unroll
      for (int h = 0; h < 4; h++) { q[2*h] = qv[h][0]; q[2*h+1] = qv[h][1]; }
      float sq[8];
      #pragma unroll
      for (int o = 0; o < 8; o++) sq[o] = mij ? q[o] : 0.f;
      #pragma unroll
      for (int off = 1; off < 32; off <<= 1) {
        #pragma unroll
        for (int o = 0; o < 8; o++) sq[o] += __shfl_xor(sq[o], off, 32);
      }
      float qd[8];
      #pragma unroll
      for (int o = 0; o < 8; o++) qd[o] = __shfl(q[o], i, 32);
      float F[8];
      if (diag) {
        #pragma unroll
        for (int o = 0; o < 8; o++) F[o] = fmaxf(sq[o]*in_, 0.f);
      } else {
        float scl = mij ? 0.5f : 1.0f;
        #pragma unroll
        for (int o = 0; o < 8; o++)
          F[o] = fmaxf((q[o] + (mij ? qd[o] : 0.f))*scl, 0.f);
      }
      #pragma unroll
      for (int off = 1; off < 32; off <<= 1) {
        #pragma unroll
        for (int o = 0; o < 8; o++) F[o] = fmaxf(F[o], __shfl_xor(F[o], off, 32));
      }
      if (j == 0) {
        #pragma unroll
        for (int o = 0; o < 8; o++) phbuf[i][myM*GO + o] = F[o];
      }
    }
    __syncthreads();

    // ---- exchange pooled half with partner block (double-buffered by t parity) ----
    {
      int sl  = (mybase + (t & 1))*SLOT;
      int psl = (pbase  + (t & 1))*SLOT;
      if (tid < 256) {
        int p = tid >> 3, o = tid & 7;
        atomicExch(ws + sl + tid, phbuf[p][myM*8 + o]);
      }
      __syncthreads();   // drains vmcnt in every wave -> data globally visible
      if (tid == 0) {
        atomicExch((unsigned*)(ws + sl + 256), (unsigned)(t + 1));
        while (atomicAdd((unsigned*)(ws + psl + 256), 0u) != (unsigned)(t + 1))
          __builtin_amdgcn_s_sleep(2);
      }
      __syncthreads();
      if (tid < 256) {
        int p = tid >> 3, o = tid & 7;
        phbuf[p][(1-myM)*8 + o] = atomicAdd(ws + psl + tid, 0.0f);
      }
    }
    __syncthreads();

    // P4: mlp (48 -> 64 -> 32, relu both). 32 lanes per ped (redundant in both blocks).
    {
      int p = grp32, u = lane;
      float in48[48];
      #pragma unroll
      for (int c = 0; c < 8; c++) {
        float4 v = *(const float4*)&h2buf[p][c*4];
        in48[c*4+0]=v.x; in48[c*4+1]=v.y; in48[c*4+2]=v.z; in48[c*4+3]=v.w;
      }
      #pragma unroll
      for (int c = 0; c < 4; c++) {
        float4 v = *(const float4*)&phbuf[p][c*4];
        in48[32+c*4+0]=v.x; in48[32+c*4+1]=v.y; in48[32+c*4+2]=v.z; in48[32+c*4+3]=v.w;
      }
      float m1lo = bm1l[u], m1hi = bm1l[32 + u];
      #pragma unroll
      for (int k = 0; k < 48; k++) {
        unsigned v = Wm1p[k][u];
        m1lo = fmaf(in48[k], lo16(v), m1lo);
        m1hi = fmaf(in48[k], hi16(v), m1hi);
      }
      m1lo = fmaxf(m1lo, 0.f); m1hi = fmaxf(m1hi, 0.f);
      float acc = bm2l[u];
      #pragma unroll
      for (int k = 0; k < 32; k++) {
        unsigned v = Wm2p[k][u];
        acc = fmaf(__shfl(m1lo, k, 32), lo16(v), acc);
        acc = fmaf(__shfl(m1hi, k, 32), hi16(v), acc);
      }
      hbuf[p][u] = fmaxf(acc, 0.f);
    }
    __syncthreads();
  }
}

// ==================== mono fallback: 128 blocks (R4 kernel, verified) ====================
__global__ __launch_bounds__(1024, 1) void decoder_kernel_mono(
    const float* __restrict__ last_pos, const float* __restrict__ last_pos_rel,
    const float* __restrict__ hh, const float* __restrict__ ch,
    const int*  __restrict__ eg,
    const float* __restrict__ W_se, const float* __restrict__ b_se,
    const float* __restrict__ Wih, const float* __restrict__ Whh,
    const float* __restrict__ bih, const float* __restrict__ bhh,
    const float* __restrict__ W_hp, const float* __restrict__ b_hp,
    const float* __restrict__ W_pse, const float* __restrict__ b_pse,
    const float* __restrict__ W1a, const float* __restrict__ W2a,
    const float* __restrict__ W1b, const float* __restrict__ W2b,
    const float* __restrict__ W_m1, const float* __restrict__ b_m1,
    const float* __restrict__ W_m2, const float* __restrict__ b_m2,
    float* __restrict__ out)
{
  const int tid   = threadIdx.x;
  const int scn   = blockIdx.x;
  const int lane  = tid & 31;
  const int grp32 = tid >> 5;

  __shared__ __align__(16) float uni[4864];
  __shared__ __align__(16) unsigned W1p[2][16][GH];
  __shared__ __align__(16) float W2l[2][GH][GO];
  __shared__ __align__(16) float Wp1[2][2][GH];
  __shared__ __align__(16) float c1l[2][GH];
  __shared__ __align__(16) float hbuf[NP][HD];
  __shared__ __align__(16) float h2buf[NP][36];
  __shared__ __align__(16) float GS[2][5][GH];
  __shared__ __align__(16) float phbuf[NP][16];
  __shared__ __align__(16) unsigned Wm1p[48][32];
  __shared__ __align__(16) unsigned Wm2p[32][32];
  __shared__ float lpbuf[NP][2], rpbuf[NP][2], Whp[HD][2];
  __shared__ float bm1l[MD], bm2l[HD], bhp2[2];
  __shared__ unsigned bm[2][NP];
  __shared__ float invn[2][NP];
  __shared__ int gl[NP];

  const int myrow = tid & 127;
  const int pq4   = tid >> 7;
  float wrow[HD];
  #pragma unroll
  for (int c = 0; c < HD/4; c++) {
    float4 w = *(const float4*)(Whh + myrow*HD + c*4);
    wrow[c*4+0]=w.x; wrow[c*4+1]=w.y; wrow[c*4+2]=w.z; wrow[c*4+3]=w.w;
  }
  float wf0 = 0.f, wf1 = 0.f, bfr = bih[myrow] + bhh[myrow];
  #pragma unroll
  for (int e = 0; e < ED; e++) {
    float wv = Wih[myrow*ED + e];
    wf0 = fmaf(W_se[e],    wv, wf0);
    wf1 = fmaf(W_se[ED+e], wv, wf1);
    bfr = fmaf(b_se[e],    wv, bfr);
  }
  float creg = ch[(scn*NP + grp32)*HD + lane];
  hbuf[grp32][lane] = hh[(scn*NP + grp32)*HD + lane];

  if (tid < NP) {
    int gi = eg[scn*NP + tid];
    gl[tid] = gi;
    unsigned sm = 0;
    for (int j = 0; j < NP; j++) {
      int gj = eg[scn*NP + j];
      bool sj = (j == tid) || (gi == gj && gi != 0);
      sm |= ((unsigned)sj) << j;
    }
    unsigned dm = (~sm) | (1u << tid);
    bm[0][tid] = sm; bm[1][tid] = dm;
    invn[0][tid] = 1.0f/(float)__popc(sm);
    invn[1][tid] = 1.0f/(float)__popc(dm);
  }
  if (tid < 64) {
    int p = tid >> 1, k = tid & 1;
    lpbuf[p][k] = last_pos[(scn*NP+p)*2+k];
    rpbuf[p][k] = last_pos_rel[(scn*NP+p)*2+k];
    Whp[p][k]   = W_hp[tid];
    bm1l[tid]   = b_m1[tid];
  }
  if (tid < 32) bm2l[tid] = b_m2[tid];
  if (tid < 2)  bhp2[tid] = b_hp[tid];
  if (tid < 2*GH) {
    int m = tid / GH, d = tid % GH;
    const float* W1 = m ? W1b : W1a;
    float s0 = 0.f, s1 = 0.f, sc1 = 0.f;
    for (int e = 0; e < ED; e++) {
      float w = W1[e*GH + d];
      s0 += W_pse[e]*w; s1 += W_pse[ED+e]*w; sc1 += b_pse[e]*w;
    }
    Wp1[m][0][d] = s0; Wp1[m][1][d] = s1; c1l[m][d] = sc1;
  }
  {
    int u = tid;
    if (u < 2*GH*GO) {
      int m = u/(GH*GO), rest = u%(GH*GO);
      W2l[m][rest/GO][rest%GO] = (m ? W2b : W2a)[rest];
    }
    if (tid < 128) {
      int u2 = tid + 1024;
      int m = u2/(GH*GO), rest = u2%(GH*GO);
      W2l[m][rest/GO][rest%GO] = (m ? W2b : W2a)[rest];
    }
  }
  #pragma unroll
  for (int r = 0; r < 3; r++) {
    int u = tid + 1024*r;
    if (u < 2304) {
      int m = u/1152, rest = u%1152, k2 = rest/GH, d = rest%GH;
      const float* W1 = m ? W1b : W1a;
      W1p[m][k2][d] = rne16(W1[(ED+2*k2)*GH + d]) | (rne16(W1[(ED+2*k2+1)*GH + d]) << 16);
    }
  }
  #pragma unroll
  for (int r = 0; r < 2; r++) {
    int u = tid + 1024*r;
    if (u < 1536) {
      int k = u >> 5, uu = u & 31;
      Wm1p[k][uu] = rne16(W_m1[k*MD + uu]) | (rne16(W_m1[k*MD + 32 + uu]) << 16);
    }
  }
  {
    int k = tid >> 5, uu = tid & 31;
    Wm2p[k][uu] = rne16(W_m2[k*HD + uu]) | (rne16(W_m2[(k+32)*HD + uu]) << 16);
  }
  __syncthreads();

  for (int t = 0; t < TT; t++) {
    {
      float rG[4];
      #pragma unroll
      for (int pp2 = 0; pp2 < 4; pp2++) {
        int p = pq4*4 + pp2;
        float acc = fmaf(rpbuf[p][0], wf0, fmaf(rpbuf[p][1], wf1, bfr));
        #pragma unroll
        for (int c = 0; c < 8; c++) {
          float4 h4 = *(const float4*)&hbuf[p][c*4];
          acc = fmaf(h4.x, wrow[c*4+0], acc);
          acc = fmaf(h4.y, wrow[c*4+1], acc);
          acc = fmaf(h4.z, wrow[c*4+2], acc);
          acc = fmaf(h4.w, wrow[c*4+3], acc);
        }
        rG[pp2] = acc;
      }
      #pragma unroll
      for (int pp2 = 0; pp2 < 4; pp2++) uni[(pq4*4+pp2)*128 + myrow] = rG[pp2];
    }
    __syncthreads();
    {
      int p = grp32, n = lane;
      float gi_ = uni[p*128 + n];
      float gf_ = uni[p*128 + 32 + n];
      float gg_ = uni[p*128 + 64 + n];
      float go_ = uni[p*128 + 96 + n];
      float c2 = sigm(gf_)*creg + sigm(gi_)*tanhfast(gg_);
      creg = c2;
      float h2 = sigm(go_)*tanhfast(c2);
      h2buf[p][n] = h2;
      float r0 = h2 * Whp[n][0];
      float r1 = h2 * Whp[n][1];
      #pragma unroll
      for (int off = 1; off < 32; off <<= 1) {
        r0 += __shfl_xor(r0, off, 32);
        r1 += __shfl_xor(r1, off, 32);
      }
      r0 += bhp2[0]; r1 += bhp2[1];
      if (n == 0) {
        out[t*NB*2 + (scn*NP+p)*2 + 0] = r0;
        out[t*NB*2 + (scn*NP+p)*2 + 1] = r1;
        rpbuf[p][0] = r0;  rpbuf[p][1] = r1;
        lpbuf[p][0] += r0; lpbuf[p][1] += r1;
      }
    }
    __syncthreads();
    {
      const int j = lane;
      float lpj0 = lpbuf[j][0], lpj1 = lpbuf[j][1];
      float h2row[HD];
      #pragma unroll
      for (int c = 0; c < 8; c++) {
        float4 v = *(const float4*)&h2buf[j][c*4];
        h2row[c*4+0]=v.x; h2row[c*4+1]=v.y; h2row[c*4+2]=v.z; h2row[c*4+3]=v.w;
      }
      #pragma unroll
      for (int r = 0; r < 5; r++) {
        int rest = grp32 + 32*r;
        if (rest < 144) {
          int m = rest >= 72 ? 1 : 0;
          int d = rest - 72*m;
          float pp_ = fmaf(lpj0, Wp1[m][0][d], lpj1*Wp1[m][1][d]);
          float av = pp_;
          #pragma unroll
          for (int k2 = 0; k2 < 16; k2++) {
            unsigned v = W1p[m][k2][d];
            av = fmaf(h2row[2*k2], lo16(v), av);
            av = fmaf(h2row[2*k2+1], hi16(v), av);
          }
          uni[m*2432 + j*76 + d] = av;
          int gj = gl[j];
          float tot = av;
          float s1 = (gj==1)?av:0.f, s2=(gj==2)?av:0.f, s3=(gj==3)?av:0.f, s4=(gj==4)?av:0.f;
          #pragma unroll
          for (int off = 1; off < 32; off <<= 1) {
            tot += __shfl_xor(tot, off, 32);
            s1 += __shfl_xor(s1, off, 32);
            s2 += __shfl_xor(s2, off, 32);
            s3 += __shfl_xor(s3, off, 32);
            s4 += __shfl_xor(s4, off, 32);
          }
          if (j < 5) {
            float v2;
            if (m == 0) v2 = (j==0)?tot:((j==1)?s1:((j==2)?s2:((j==3)?s3:s4)));
            else        v2 = (j==0)?tot:((j==1)?tot-s1:((j==2)?tot-s2:((j==3)?tot-s3:tot-s4)));
            GS[m][j][d] = v2;
          }
        }
      }
    }
    __syncthreads();
    {
      const int j   = lane;
      const int m   = tid >> 9;
      const int sub = (tid >> 5) & 15;
      const float* am = uni + m*2432;
      int   I2[2] = {sub, sub + 16};
      const float *P0[2], *P1[2];
      float C0[2], C1[2], NL0[2], NL1[2];
      bool  MIJ[2], DIAG[2];
      v2f qv[2][4];
      #pragma unroll
      for (int r = 0; r < 2; r++) {
        int i = I2[r];
        unsigned bmv = bm[m][i];
        bool mij = (bmv >> j) & 1u;
        bool diag = (j == i);
        int gi = gl[i];
        float in_ = invn[m][i];
        const float *p0, *p1; float c0, c1c;
        if (diag) {
          if (m == 0) { p0 = gi ? &GS[0][gi][0] : (am + i*76); c0 = in_; p1 = am + i*76; c1c = 0.f; }
          else        { p0 = &GS[1][gi][0];                    c0 = in_; p1 = am + i*76; c1c = gi ? in_ : 0.f; }
        } else if (mij) { p0 = am + j*76; c0 = 0.5f; p1 = am + i*76; c1c = 0.5f; }
        else            { p0 = am + j*76; c0 = 1.0f; p1 = am + j*76; c1c = 0.f; }
        P0[r]=p0; P1[r]=p1; C0[r]=c0; C1[r]=c1c; MIJ[r]=mij; DIAG[r]=diag;
        NL0[r] = -lpbuf[i][0]; NL1[r] = -lpbuf[i][1];
        #pragma unroll
        for (int h = 0; h < 4; h++) qv[r][h] = (v2f){0.f, 0.f};
      }
      for (int d4 = 0; d4 < GH/4; d4++) {
        float4 c14 = *(const float4*)&c1l[m][d4*4];
        float4 w04 = *(const float4*)&Wp1[m][0][d4*4];
        float4 w14 = *(const float4*)&Wp1[m][1][d4*4];
        float4 vaS = *(const float4*)(am + j*76 + d4*4);
        float4 va0 = vaS, va1 = vaS;
        if (DIAG[0]) va0 = *(const float4*)(P0[0] + d4*4);
        if (DIAG[1]) va1 = *(const float4*)(P0[1] + d4*4);
        float4 vb0 = *(const float4*)(P1[0] + d4*4);
        float4 vb1 = *(const float4*)(P1[1] + d4*4);
        float e0x = fmaf(NL1[0], w14.x, fmaf(NL0[0], w04.x, c14.x));
        float e0y = fmaf(NL1[0], w14.y, fmaf(NL0[0], w04.y, c14.y));
        float e0z = fmaf(NL1[0], w14.z, fmaf(NL0[0], w04.z, c14.z));
        float e0w = fmaf(NL1[0], w14.w, fmaf(NL0[0], w04.w, c14.w));
        float e1x = fmaf(NL1[1], w14.x, fmaf(NL0[1], w04.x, c14.x));
        float e1y = fmaf(NL1[1], w14.y, fmaf(NL0[1], w04.y, c14.y));
        float e1z = fmaf(NL1[1], w14.z, fmaf(NL0[1], w04.z, c14.z));
        float e1w = fmaf(NL1[1], w14.w, fmaf(NL0[1], w04.w, c14.w));
        float tv0[4], tv1[4];
        tv0[0] = fmaxf(fmaf(C0[0], va0.x, fmaf(C1[0], vb0.x, e0x)), 0.f);
        tv0[1] = fmaxf(fmaf(C0[0], va0.y, fmaf(C1[0], vb0.y, e0y)), 0.f);
        tv0[2] = fmaxf(fmaf(C0[0], va0.z, fmaf(C1[0], vb0.z, e0z)), 0.f);
        tv0[3] = fmaxf(fmaf(C0[0], va0.w, fmaf(C1[0], vb0.w, e0w)), 0.f);
        tv1[0] = fmaxf(fmaf(C0[1], va1.x, fmaf(C1[1], vb1.x, e1x)), 0.f);
        tv1[1] = fmaxf(fmaf(C0[1], va1.y, fmaf(C1[1], vb1.y, e1y)), 0.f);
        tv1[2] = fmaxf(fmaf(C0[1], va1.z, fmaf(C1[1], vb1.z, e1z)), 0.f);
        tv1[3] = fmaxf(fmaf(C0[1], va1.w, fmaf(C1[1], vb1.w, e1w)), 0.f);
        #pragma unroll
        for (int k = 0; k < 4; k++) {
          const v2f* w2p = (const v2f*)&W2l[m][d4*4+k][0];
          v2f wA = w2p[0], wB = w2p[1], wC = w2p[2], wD = w2p[3];
          v2f t0 = {tv0[k], tv0[k]};
          qv[0][0] += t0*wA; qv[0][1] += t0*wB; qv[0][2] += t0*wC; qv[0][3] += t0*wD;
          v2f t1 = {tv1[k], tv1[k]};
          qv[1][0] += t1*wA; qv[1][1] += t1*wB; qv[1][2] += t1*wC; qv[1][3] += t1*wD;
        }
      }
      #pragma unroll
      for (int r = 0; r < 2; r++) {
        float q[8];
        #pragma unroll
        for (int h = 0; h < 4; h++) { q[2*h] = qv[r][h][0]; q[2*h+1] = qv[r][h][1]; }
        float sq[8];
        #pragma unroll
        for (int o = 0; o < 8; o++) sq[o] = MIJ[r] ? q[o] : 0.f;
        #pragma unroll
        for (int off = 1; off < 32; off <<= 1) {
          #pragma unroll
          for (int o = 0; o < 8; o++) sq[o] += __shfl_xor(sq[o], off, 32);
        }
        float qd[8];
        #pragma unroll
        for (int o = 0; o < 8; o++) qd[o] = __shfl(q[o], I2[r], 32);
        float in_ = invn[m][I2[r]];
        float F[8];
        if (DIAG[r]) {
          #pragma unroll
          for (int o = 0; o < 8; o++) F[o] = fmaxf(sq[o]*in_, 0.f);
        } else {
          float scl = MIJ[r] ? 0.5f : 1.0f;
          #pragma unroll
          for (int o = 0; o < 8; o++)
            F[o] = fmaxf((q[o] + (MIJ[r] ? qd[o] : 0.f))*scl, 0.f);
        }
        #pragma unroll
        for (int off = 1; off < 32; off <<= 1) {
          #pragma unroll
          for (int o = 0; o < 8; o++) F[o] = fmaxf(F[o], __shfl_xor(F[o], off, 32));
        }
        if (j == 0) {
          #pragma unroll
          for (int o = 0; o < 8; o++) phbuf[I2[r]][m*GO + o] = F[o];
        }
      }
    }
    __syncthreads();
    {
      int p = grp32, u = lane;
      float in48[48];
      #pragma unroll
      for (int c = 0; c < 8; c++) {
        float4 v = *(const float4*)&h2buf[p][c*4];
        in48[c*4+0]=v.x; in48[c*4+1]=v.y; in48[c*4+2]=v.z; in48[c*4+3]=v.w;
      }
      #pragma unroll
      for (int c = 0; c < 4; c++) {
        float4 v = *(const float4*)&phbuf[p][c*4];
        in48[32+c*4+0]=v.x; in48[32+c*4+1]=v.y; in48[32+c*4+2]=v.z; in48[32+c*4+3]=v.w;
      }
      float m1lo = bm1l[u], m1hi = bm1l[32 + u];
      #pragma unroll
      for (int k = 0; k < 48; k++) {
        unsigned v = Wm1p[k][u];
        m1lo = fmaf(in48[k], lo16(v), m1lo);
        m1hi = fmaf(in48[k], hi16(v), m1hi);
      }
      m1lo = fmaxf(m1lo, 0.f); m1hi = fmaxf(m1hi, 0.f);
      float acc = bm2l[u];
      #pragma unroll
      for (int k = 0; k < 32; k++) {
        unsigned v = Wm2p[k][u];
        acc = fmaf(__shfl(m1lo, k, 32), lo16(v), acc);
        acc = fmaf(__shfl(m1hi, k, 32), hi16(v), acc);
      }
      hbuf[p][u] = fmaxf(acc, 0.f);
    }
    __syncthreads();
  }
}

extern "C" void kernel_launch(void* const* d_in, const int* in_sizes, int n_in,
                              void* d_out, int out_size, void* d_ws, size_t ws_size,
                              hipStream_t stream) {
  (void)in_sizes; (void)n_in; (void)out_size;
  const float* last_pos     = (const float*)d_in[0];
  const float* last_pos_rel = (const float*)d_in[1];
  const float* hh           = (const float*)d_in[2];
  const float* ch           = (const float*)d_in[3];
  const int*  eg            = (const int*) d_in[5];
  const float* W_se  = (const float*)d_in[6];
  const float* b_se  = (const float*)d_in[7];
  const float* Wih   = (const float*)d_in[8];
  const float* Whh   = (const float*)d_in[9];
  const float* bih   = (const float*)d_in[10];
  const float* bhh   = (const float*)d_in[11];
  const float* W_hp  = (const float*)d_in[12];
  const float* b_hp  = (const float*)d_in[13];
  const float* W_pse = (const float*)d_in[14];
  const float* b_pse = (const float*)d_in[15];
  const float* W1a   = (const float*)d_in[16];
  const float* W2a   = (const float*)d_in[17];
  const float* W1b   = (const float*)d_in[18];
  const float* W2b   = (const float*)d_in[19];
  const float* W_m1  = (const float*)d_in[20];
  const float* b_m1  = (const float*)d_in[21];
  const float* W_m2  = (const float*)d_in[22];
  const float* b_m2  = (const float*)d_in[23];
  float* out = (float*)d_out;

  if (ws_size >= (size_t)WS_NEED) {
    decoder_kernel_split<<<2*NS, 1024, 0, stream>>>(
        last_pos, last_pos_rel, hh, ch, eg,
        W_se, b_se, Wih, Whh, bih, bhh, W_hp, b_hp, W_pse, b_pse,
        W1a, W2a, W1b, W2b, W_m1, b_m1, W_m2, b_m2, out, (float*)d_ws);
  } else {
    decoder_kernel_mono<<<NS, 1024, 0, stream>>>(
        last_pos, last_pos_rel, hh, ch, eg,
        W_se, b_se, Wih, Whh, bih, bhh, W_hp, b_hp, W_pse, b_pse,
        W1a, W2a, W1b, W2b, W_m1, b_m1, W_m2, b_m2, out);
  }
}